// Round 10
// baseline (39.886 us; speedup 1.0000x reference)
//
#include <hip/hip_runtime.h>

// BilinearSampler: B=128, H=256, W=256, C=3
// Input row layout: [theta(6) | image(H*W*C)] per batch, f32.
//
// Model (fits r4/r7/r8/r9): wall = VALU-time + TA-gather-time ~ 39us,
// non-overlapping (per-wave chain addr->gather->combine at ~11 waves/CU).
// r10: cut VALU via packed-FP32. Each lane-pair computes 2 pixels per
// iteration; all coordinate/weight/combine math in f32x2 so clang emits
// v_pk_fma_f32/v_pk_mul_f32/v_pk_add_f32 (full rate, half the instrs for
// the packable ~60%). Gather addresses/instruction count unchanged.
// All fp expressions string-identical to r8/r9 -> bit-identical output.

constexpr int BB = 128;
constexpr int HH = 256;
constexpr int WW = 256;
constexpr int CC = 3;
constexpr long long IMG_ELEMS = (long long)HH * WW * CC;   // 196608
constexpr long long ROW_ELEMS = 6 + IMG_ELEMS;             // 196614
constexpr int NWG = BB * 32;                               // 4096 blocks, %8==0
constexpr int LDSW = 98;  // 32 px = 96 floats + 2 pad (case-B staging row)

typedef float f32x2 __attribute__((ext_vector_type(2)));
struct F3 { float v[3]; };
struct __attribute__((aligned(8))) F6s { float v[6]; };

__device__ __forceinline__ f32x2 floor2(f32x2 a) {
    return (f32x2){floorf(a.x), floorf(a.y)};
}
__device__ __forceinline__ f32x2 clamp2(f32x2 a) {
    return (f32x2){fminf(fmaxf(a.x, 0.0f), (float)(WW - 1)),
                   fminf(fmaxf(a.y, 0.0f), (float)(WW - 1))};
}

struct SC2 {
    int yloP, yhiP, yloQ, yhiQ;
    int col0P, col1P, col0Q, col1Q;
    f32x2 wlo0, whi0, wlo1, whi1;   // component .x = pixel P, .y = pixel Q
};

__device__ __forceinline__ SC2 make_scoord2(
    float t00, float t01, float t02, float t10, float t11, float t12,
    f32x2 xt, f32x2 yt)
{
    SC2 q;
    // Same expression strings as the passing r8/r9 scalar path; packed ops
    // are component-wise IEEE-identical.
    f32x2 x_s = t00 * xt + t01 * yt + t02;
    f32x2 y_s = t10 * xt + t11 * yt + t12;
    f32x2 x = 0.5f * (x_s + 1.0f) * (float)(WW - 1);
    f32x2 y = 0.5f * (y_s + 1.0f) * (float)(HH - 1);

    f32x2 xf = floor2(x);
    f32x2 yf = floor2(y);
    f32x2 x0f = clamp2(xf);
    f32x2 x1f = clamp2(xf + 1.0f);
    f32x2 y0f = clamp2(yf);
    f32x2 y1f = clamp2(yf + 1.0f);

    q.col0P = (int)x0f.x;  q.col0Q = (int)x0f.y;
    q.col1P = (int)x1f.x;  q.col1Q = (int)x1f.y;
    q.yloP  = (int)y0f.x;  q.yloQ  = (int)y0f.y;
    q.yhiP  = (int)y1f.x;  q.yhiQ  = (int)y1f.y;

    q.wlo0 = (x1f - x) * (y1f - y);   // wa  ([ylo][col0])
    q.whi0 = (x1f - x) * (y - y0f);   // wb  ([yhi][col0])
    q.wlo1 = (x - x0f) * (y1f - y);   // wc  ([ylo][col1])
    q.whi1 = (x - x0f) * (y - y0f);   // wd  ([yhi][col1])
    return q;
}

// Lane pair (2i,2i+1) jointly computes TWO pixels' 3 channels (packed).
__device__ __forceinline__ void pair_sample2(
    const float* __restrict__ img, const SC2& q, int odd, f32x2 o[3])
{
    const int colP = odd ? q.col1P : q.col0P;
    const int colQ = odd ? q.col1Q : q.col0Q;
    const f32x2 wlo = odd ? q.wlo1 : q.wlo0;
    const f32x2 whi = odd ? q.whi1 : q.whi0;
    const F3 vloP = *reinterpret_cast<const F3*>(img + (q.yloP * WW + colP) * CC);
    const F3 vhiP = *reinterpret_cast<const F3*>(img + (q.yhiP * WW + colP) * CC);
    const F3 vloQ = *reinterpret_cast<const F3*>(img + (q.yloQ * WW + colQ) * CC);
    const F3 vhiQ = *reinterpret_cast<const F3*>(img + (q.yhiQ * WW + colQ) * CC);
    #pragma unroll
    for (int c = 0; c < 3; ++c) {
        const f32x2 vlo = {vloP.v[c], vloQ.v[c]};
        const f32x2 vhi = {vhiP.v[c], vhiQ.v[c]};
        const f32x2 part = wlo * vlo + whi * vhi;   // pk_mul + pk_fma
        f32x2 sum;
        sum.x = part.x + __shfl_xor(part.x, 1, 64);
        sum.y = part.y + __shfl_xor(part.y, 1, 64);
        o[c] = sum;
    }
}

__global__ __launch_bounds__(256) void bilinear_sampler_kernel(
    const float* __restrict__ in, float* __restrict__ out)
{
    __shared__ float lds[64 * LDSW];   // 25088 B (case-B staging)

    // XCD-chunked bijective swizzle (4096 % 8 == 0).
    const int bid = blockIdx.x;
    const int swz = (bid & 7) * (NWG >> 3) + (bid >> 3);
    const int b    = swz >> 5;        // batch
    const int beta = swz & 31;        // block-within-batch

    const float* __restrict__ base = in + (long long)b * ROW_ELEMS;
    const float t00 = base[0], t01 = base[1], t02 = base[2];
    const float t10 = base[3], t11 = base[4], t12 = base[5];
    const float* __restrict__ img = base + 6;
    float* __restrict__ outb = out + (long long)b * IMG_ELEMS;

    const int tid = threadIdx.x;
    const int v   = tid >> 6;         // wave index 0..3
    const int l   = tid & 63;         // lane
    const int i   = l >> 1;           // pair index 0..31
    const int odd = l & 1;

    // Per-instruction line estimate: rows term (32|ty|) + x-span term (6|tx|).
    const float costA = 32.0f * fabsf(t10) + 6.0f * fabsf(t00);
    const float costB = 32.0f * fabsf(t11) + 6.0f * fabsf(t01);

    if (costA <= costB) {
        // ---- Case A: pixels run along w; pair handles adjacent (wP, wP+1). ----
        // Block tile: 256w x 8h. Wave v owns rows {h0+2v, h0+2v+1}.
        const int h0 = beta * 8;
        #pragma unroll 2
        for (int f = 0; f < 8; ++f) {
            const int row = h0 + 2 * v + (f >> 2);
            const int wP  = ((f & 3) << 6) + 2 * i;       // even col 0..255
            const f32x2 xt = { -1.0f + (2.0f / (WW - 1)) * (float)wP,
                               -1.0f + (2.0f / (WW - 1)) * (float)(wP + 1) };
            const float ytv = -1.0f + (2.0f / (HH - 1)) * (float)row;
            const f32x2 yt = {ytv, ytv};
            const SC2 q = make_scoord2(t00, t01, t02, t10, t11, t12, xt, yt);
            f32x2 o[3];
            pair_sample2(img, q, odd, o);
            if (!odd) {
                F6s s;
                s.v[0] = o[0].x; s.v[1] = o[1].x; s.v[2] = o[2].x;
                s.v[3] = o[0].y; s.v[4] = o[1].y; s.v[5] = o[2].y;
                *reinterpret_cast<F6s*>(outb + (row * WW + wP) * CC) = s;
            }
        }
    } else {
        // ---- Case B: pixels run along h; pair handles rows (i, i+32). ----
        // Block tile: 32w x 64h; staged in LDS, stored coalesced.
        const int h0 = (beta & 3) * 64;
        const int w0 = (beta >> 2) * 32;
        #pragma unroll 2
        for (int f = 0; f < 8; ++f) {
            const int cpx = 8 * v + f;                    // block-local col
            const float xtv = -1.0f + (2.0f / (WW - 1)) * (float)(w0 + cpx);
            const f32x2 xt = {xtv, xtv};
            const f32x2 yt = { -1.0f + (2.0f / (HH - 1)) * (float)(h0 + i),
                               -1.0f + (2.0f / (HH - 1)) * (float)(h0 + i + 32) };
            const SC2 q = make_scoord2(t00, t01, t02, t10, t11, t12, xt, yt);
            f32x2 o[3];
            pair_sample2(img, q, odd, o);
            if (!odd) {
                float* dP = &lds[i * LDSW + cpx * 3];
                dP[0] = o[0].x; dP[1] = o[1].x; dP[2] = o[2].x;
                float* dQ = &lds[(i + 32) * LDSW + cpx * 3];
                dQ[0] = o[0].y; dQ[1] = o[1].y; dQ[2] = o[2].y;
            }
        }
        __syncthreads();
        // Store phase: tile row r = 32 px = 96 dwords = 48 dword-pairs.
        #pragma unroll
        for (int p = 0; p < 12; ++p) {
            const int d2 = p * 256 + tid;     // pair index 0..3071
            const int r  = d2 / 48;
            const int k  = d2 % 48;
            const f32x2 val = *reinterpret_cast<const f32x2*>(&lds[r * LDSW + k * 2]);
            *reinterpret_cast<f32x2*>(
                outb + (h0 + r) * (WW * CC) + w0 * CC + k * 2) = val;
        }
    }
}

extern "C" void kernel_launch(void* const* d_in, const int* in_sizes, int n_in,
                              void* d_out, int out_size, void* d_ws, size_t ws_size,
                              hipStream_t stream)
{
    const float* in = (const float*)d_in[0];
    float* out = (float*)d_out;
    dim3 grid(NWG), block(256);
    bilinear_sampler_kernel<<<grid, block, 0, stream>>>(in, out);
}

// Round 11
// 38.299 us; speedup vs baseline: 1.0414x; 1.0414x over previous
//
#include <hip/hip_runtime.h>

// BilinearSampler: B=128, H=256, W=256, C=3
// Input row layout: [theta(6) | image(H*W*C)] per batch, f32.
//
// FINAL (revert to r9, the best-measured variant at 38.5us).
//
// Model established over r4-r10: wall = vector-memory scatter path,
// ~37 cyc per scattered VMEM wave-instruction (quad-granular line replay,
// ~2-3 lines/quad, floor is 2 = the two y-levels each pixel needs).
// 4 gather instructions per 64 px is coverage-minimal (48B/px, <=16B lane
// loads). Wall invariant under occupancy 20-77%, VALU 16-39%, MLP 4-32,
// FETCH 17-105MB. r10's packed-FP32 cut VALU but regressed the wall ->
// VALU fully hidden; revert.
//
// Techniques retained: adaptive lane-walk direction by per-instruction
// line estimate 32|ty|+6|tx| (r4/r9); lane-pair column split with
// __shfl_xor combine (r8); XCD-chunked bijective block swizzle (r3);
// LDS-staged coalesced stores for the column-walk case (r4);
// float-domain med3 clamps (r9).

constexpr int BB = 128;
constexpr int HH = 256;
constexpr int WW = 256;
constexpr int CC = 3;
constexpr long long IMG_ELEMS = (long long)HH * WW * CC;   // 196608
constexpr long long ROW_ELEMS = 6 + IMG_ELEMS;             // 196614
constexpr int NWG = BB * 32;                               // 4096 blocks, %8==0
constexpr int LDSW = 98;  // 32 px = 96 floats + 2 pad (case-B staging row)

typedef float f32x2 __attribute__((ext_vector_type(2)));
struct F3 { float v[3]; };

struct SCoord {
    int ylo, yhi;      // clipped rows
    int col0, col1;    // clipped x0c, x1c
    float wlo0, whi0;  // weights for the x0c column (wa, wb)
    float wlo1, whi1;  // weights for the x1c column (wc, wd)
};

__device__ __forceinline__ SCoord make_scoord(
    float t00, float t01, float t02, float t10, float t11, float t12,
    int w, int h)
{
    SCoord q;
    const float xt = -1.0f + (2.0f / (WW - 1)) * (float)w;
    const float yt = -1.0f + (2.0f / (HH - 1)) * (float)h;
    const float x_s = t00 * xt + t01 * yt + t02;
    const float y_s = t10 * xt + t11 * yt + t12;
    const float x = 0.5f * (x_s + 1.0f) * (float)(WW - 1);
    const float y = 0.5f * (y_s + 1.0f) * (float)(HH - 1);

    // floor() results are exact integers in f32, so clamping in float is
    // bit-identical to the reference's int clamp -> v_med3_f32 each.
    const float xf = floorf(x);
    const float yf = floorf(y);
    const float x0f = fminf(fmaxf(xf,         0.0f), 255.0f);
    const float x1f = fminf(fmaxf(xf + 1.0f,  0.0f), 255.0f);
    const float y0f = fminf(fmaxf(yf,         0.0f), 255.0f);
    const float y1f = fminf(fmaxf(yf + 1.0f,  0.0f), 255.0f);

    q.col0 = (int)x0f;
    q.col1 = (int)x1f;
    q.ylo  = (int)y0f;
    q.yhi  = (int)y1f;

    q.wlo0 = (x1f - x) * (y1f - y);   // wa  (Ia = [ylo][col0])
    q.whi0 = (x1f - x) * (y - y0f);   // wb  (Ib = [yhi][col0])
    q.wlo1 = (x - x0f) * (y1f - y);   // wc  (Ic = [ylo][col1])
    q.whi1 = (x - x0f) * (y - y0f);   // wd  (Id = [yhi][col1])
    return q;
}

// Lane pair (2i, 2i+1) jointly computes one pixel's 3 channels; the summed
// value is valid in both lanes after the xor-shuffle.
__device__ __forceinline__ void pair_sample(
    const float* __restrict__ img, const SCoord& q, int odd, float o[3])
{
    const int mycol = odd ? q.col1 : q.col0;
    const float wlo = odd ? q.wlo1 : q.wlo0;
    const float whi = odd ? q.whi1 : q.whi0;
    const F3 vlo = *reinterpret_cast<const F3*>(img + (q.ylo * WW + mycol) * CC);
    const F3 vhi = *reinterpret_cast<const F3*>(img + (q.yhi * WW + mycol) * CC);
    #pragma unroll
    for (int c = 0; c < 3; ++c) {
        const float part = wlo * vlo.v[c] + whi * vhi.v[c];
        o[c] = part + __shfl_xor(part, 1, 64);
    }
}

__global__ __launch_bounds__(256) void bilinear_sampler_kernel(
    const float* __restrict__ in, float* __restrict__ out)
{
    __shared__ float lds[64 * LDSW];   // 25088 B (case-B staging)

    // XCD-chunked bijective swizzle (4096 % 8 == 0).
    const int bid = blockIdx.x;
    const int swz = (bid & 7) * (NWG >> 3) + (bid >> 3);
    const int b    = swz >> 5;        // batch
    const int beta = swz & 31;        // block-within-batch

    const float* __restrict__ base = in + (long long)b * ROW_ELEMS;
    const float t00 = base[0], t01 = base[1], t02 = base[2];
    const float t10 = base[3], t11 = base[4], t12 = base[5];
    const float* __restrict__ img = base + 6;
    float* __restrict__ outb = out + (long long)b * IMG_ELEMS;

    const int tid = threadIdx.x;
    const int v   = tid >> 6;         // wave index 0..3
    const int l   = tid & 63;         // lane
    const int i   = l >> 1;           // pair index 0..31
    const int odd = l & 1;

    // Per-instruction line estimate: rows term (32|ty|) + x-span term (6|tx|).
    const float costA = 32.0f * fabsf(t10) + 6.0f * fabsf(t00);
    const float costB = 32.0f * fabsf(t11) + 6.0f * fabsf(t01);

    if (costA <= costB) {
        // ---- Case A: pixel runs along w. ----
        // Block tile: 256w x 8h. Wave v owns rows {h0+2v, h0+2v+1}.
        const int h0 = beta * 8;
        #pragma unroll 2
        for (int f = 0; f < 16; ++f) {
            const int row = h0 + 2 * v + (f >> 3);
            const int wpx = ((f & 7) << 5) + i;
            const SCoord q = make_scoord(t00, t01, t02, t10, t11, t12, wpx, row);
            float o[3];
            pair_sample(img, q, odd, o);
            if (!odd) {
                F3 s; s.v[0] = o[0]; s.v[1] = o[1]; s.v[2] = o[2];
                *reinterpret_cast<F3*>(outb + (row * WW + wpx) * CC) = s;
            }
        }
    } else {
        // ---- Case B: pixel runs along h. ----
        // Block tile: 32w x 64h. Wave v owns cols {w0+8v .. w0+8v+7}.
        const int h0 = (beta & 3) * 64;
        const int w0 = (beta >> 2) * 32;
        #pragma unroll 2
        for (int f = 0; f < 16; ++f) {
            const int cpx  = 8 * v + (f >> 1);          // block-local col 0..31
            const int hloc = ((f & 1) << 5) + i;        // block-local row 0..63
            const SCoord q = make_scoord(t00, t01, t02, t10, t11, t12,
                                         w0 + cpx, h0 + hloc);
            float o[3];
            pair_sample(img, q, odd, o);
            if (!odd) {
                float* dst = &lds[hloc * LDSW + cpx * 3];
                dst[0] = o[0]; dst[1] = o[1]; dst[2] = o[2];
            }
        }
        __syncthreads();
        // Store phase: tile row r = 32 px = 96 dwords = 48 dword-pairs.
        #pragma unroll
        for (int p = 0; p < 12; ++p) {
            const int d2 = p * 256 + tid;     // pair index 0..3071
            const int r  = d2 / 48;
            const int k  = d2 % 48;
            const f32x2 val = *reinterpret_cast<const f32x2*>(&lds[r * LDSW + k * 2]);
            *reinterpret_cast<f32x2*>(
                outb + (h0 + r) * (WW * CC) + w0 * CC + k * 2) = val;
        }
    }
}

extern "C" void kernel_launch(void* const* d_in, const int* in_sizes, int n_in,
                              void* d_out, int out_size, void* d_ws, size_t ws_size,
                              hipStream_t stream)
{
    const float* in = (const float*)d_in[0];
    float* out = (float*)d_out;
    dim3 grid(NWG), block(256);
    bilinear_sampler_kernel<<<grid, block, 0, stream>>>(in, out);
}